// Round 10
// baseline (162.631 us; speedup 1.0000x reference)
//
#include <hip/hip_runtime.h>
#include <hip/hip_bf16.h>
#include <stdint.h>

#define NN 100000
#define EE 1600000
#define CAP 128           // srclist slots per dst (max unique in-degree ~70)
#define NB 782            // ceil(NN/128) dst buckets
#define CAPB 5120         // bucket capacity (mean ~4092, sigma ~64)
#define HTS 8192          // per-bucket LDS hash slots
#define EMPTY 0xFFFFFFFFu
#define BCHUNK 2048       // edge pairs per bin block
#define GBIN 782          // bin blocks: ceil(EE/2048)
#define GLIN 1563         // linear blocks: ceil(NN/64)

typedef float  fx4 __attribute__((ext_vector_type(4)));   // NT-store-compatible

__device__ __forceinline__ unsigned int mix32(unsigned int x){
  x ^= x >> 16; x *= 0x7feb352du;
  x ^= x >> 15; x *= 0x846ca68bu;
  x ^= x >> 16;
  return x;
}

// Fused linear+bin, ~17.9KB LDS -> 8 blocks/CU. Bin blocks FIRST (longest-
// job-first). Bin uses one-pass slot reservation: LDS atomicAdd gives local
// pos (kept in regs), one global atomicAdd per (block,bucket) gives base.
extern "C" __global__ __launch_bounds__(256)
void k_prep(const float* __restrict__ x, const float* __restrict__ W,
            const float* __restrict__ bias, __hip_bfloat16* __restrict__ hb,
            const int* __restrict__ ei, int* __restrict__ bcnt,
            unsigned int* __restrict__ bbuf){
  __shared__ __align__(16) char sm[17920];
  const int tid = threadIdx.x;
  const int bid = blockIdx.x;
  const bool isbin = (bid < GBIN);
  const int sub = isbin ? bid : (bid - GBIN);

  if (!isbin){
    // ---------- linear: 64 nodes/block, W and x staged bf16 ----------
    __hip_bfloat16 (*wt)[72] = reinterpret_cast<__hip_bfloat16(*)[72]>(sm);        // 9216B wt[i][o]=W[o][i]
    __hip_bfloat16 (*xs)[68] = reinterpret_cast<__hip_bfloat16(*)[68]>(sm + 9216); // 8704B xs[i][n]
    const int lane = tid & 63;
    const int wv   = tid >> 6;
    #pragma unroll
    for (int r = 0; r < 16; ++r){
      int i = r*4 + wv;
      wt[i][lane] = __float2bfloat16(W[lane*64 + i]);
    }
    const int nbase = sub * 64;
    #pragma unroll
    for (int r = 0; r < 4; ++r){
      int idx = r*256 + tid;          // float4 slot in [64][16]
      int nl  = idx >> 4;
      int c4  = idx & 15;
      int n   = nbase + nl;
      float4 v = make_float4(0.f,0.f,0.f,0.f);
      if (n < NN) v = reinterpret_cast<const float4*>(x)[(size_t)n*16 + c4];
      xs[c4*4+0][nl] = __float2bfloat16(v.x);
      xs[c4*4+1][nl] = __float2bfloat16(v.y);
      xs[c4*4+2][nl] = __float2bfloat16(v.z);
      xs[c4*4+3][nl] = __float2bfloat16(v.w);
    }
    __syncthreads();

    const int og  = tid & 7;
    const int nl0 = (tid >> 3) * 2;   // 2 nodes per thread
    float acc[2][8];
    #pragma unroll
    for (int t=0;t<2;++t){
      #pragma unroll
      for (int j=0;j<8;++j) acc[t][j]=0.f;
    }
    #pragma unroll 4
    for (int i=0;i<64;++i){
      uint4 wq = *reinterpret_cast<const uint4*>(&wt[i][og*8]);
      float w0 = __uint_as_float(wq.x << 16), w1 = __uint_as_float(wq.x & 0xFFFF0000u);
      float w2 = __uint_as_float(wq.y << 16), w3 = __uint_as_float(wq.y & 0xFFFF0000u);
      float w4 = __uint_as_float(wq.z << 16), w5 = __uint_as_float(wq.z & 0xFFFF0000u);
      float w6 = __uint_as_float(wq.w << 16), w7 = __uint_as_float(wq.w & 0xFFFF0000u);
      unsigned xv = *reinterpret_cast<const unsigned*>(&xs[i][nl0]);  // 2 bf16
      float x0 = __uint_as_float(xv << 16);
      float x1 = __uint_as_float(xv & 0xFFFF0000u);
      acc[0][0] += x0*w0; acc[0][1] += x0*w1; acc[0][2] += x0*w2; acc[0][3] += x0*w3;
      acc[0][4] += x0*w4; acc[0][5] += x0*w5; acc[0][6] += x0*w6; acc[0][7] += x0*w7;
      acc[1][0] += x1*w0; acc[1][1] += x1*w1; acc[1][2] += x1*w2; acc[1][3] += x1*w3;
      acc[1][4] += x1*w4; acc[1][5] += x1*w5; acc[1][6] += x1*w6; acc[1][7] += x1*w7;
    }
    float4 b0 = reinterpret_cast<const float4*>(bias)[og*2];
    float4 b1 = reinterpret_cast<const float4*>(bias)[og*2+1];
    float bb[8] = {b0.x,b0.y,b0.z,b0.w,b1.x,b1.y,b1.z,b1.w};
    #pragma unroll
    for (int t=0;t<2;++t){
      int n = nbase + nl0 + t;
      if (n < NN){
        union { uint4 u4; __hip_bfloat16 v[8]; } pk;
        #pragma unroll
        for (int j=0;j<8;++j) pk.v[j] = __float2bfloat16(acc[t][j] + bb[j]);
        reinterpret_cast<uint4*>(&hb[(size_t)n*64])[og] = pk.u4;
      }
    }
  } else {
    // ---------- bin: 2048 pairs/block, one-pass reservation ----------
    int* bcur  = reinterpret_cast<int*>(sm);   // [NB]
    int* bbase = bcur + NB;                    // [NB]
    for (int i = tid; i < NB; i += 256) bcur[i] = 0;
    __syncthreads();
    const int e0 = sub * BCHUNK;
    const int4* ea4 = reinterpret_cast<const int4*>(ei);
    const int4* ec4 = reinterpret_cast<const int4*>(ei + EE);
    int4 A0, C0, A1, C1;
    unsigned P[8];
    {
      int idx0 = (e0 >> 2) + tid;
      int idx1 = idx0 + 256;
      if (idx0*4 < EE){ A0 = ea4[idx0]; C0 = ec4[idx0]; }
      else { A0 = make_int4(-1,-1,-1,-1); C0 = A0; }
      if (idx1*4 < EE){ A1 = ea4[idx1]; C1 = ec4[idx1]; }
      else { A1 = make_int4(-1,-1,-1,-1); C1 = A1; }
    }
#define RESV(a,c,slot) \
    if ((a) >= 0){ \
      unsigned p1 = (unsigned)atomicAdd(&bcur[(c) >> 7], 1); \
      unsigned p2 = (unsigned)atomicAdd(&bcur[(a) >> 7], 1); \
      P[slot] = p1 | (p2 << 16); \
    }
    RESV(A0.x, C0.x, 0) RESV(A0.y, C0.y, 1) RESV(A0.z, C0.z, 2) RESV(A0.w, C0.w, 3)
    RESV(A1.x, C1.x, 4) RESV(A1.y, C1.y, 5) RESV(A1.z, C1.z, 6) RESV(A1.w, C1.w, 7)
#undef RESV
    __syncthreads();
    for (int bk = tid; bk < NB; bk += 256){
      int hh = bcur[bk];
      bbase[bk] = hh ? atomicAdd(&bcnt[bk], hh) : 0;
    }
    __syncthreads();
#define PLACE(a,c,slot) \
    if ((a) >= 0){ \
      int b1 = (c) >> 7, b2 = (a) >> 7; \
      unsigned q1 = (unsigned)bbase[b1] + (P[slot] & 0xFFFFu); \
      unsigned q2 = (unsigned)bbase[b2] + (P[slot] >> 16); \
      if (q1 < CAPB) bbuf[(size_t)b1*CAPB + q1] = ((unsigned)(a) << 7) | (unsigned)((c) & 127); \
      if (q2 < CAPB) bbuf[(size_t)b2*CAPB + q2] = ((unsigned)(c) << 7) | (unsigned)((a) & 127); \
    }
    PLACE(A0.x, C0.x, 0) PLACE(A0.y, C0.y, 1) PLACE(A0.z, C0.z, 2) PLACE(A0.w, C0.w, 3)
    PLACE(A1.x, C1.x, 4) PLACE(A1.y, C1.y, 5) PLACE(A1.z, C1.z, 6) PLACE(A1.w, C1.w, 7)
#undef PLACE
  }
}

// One block per bucket: dedup in LDS hash, inject self loops, then a single
// HT scan that simultaneously compacts src lists and counts degrees.
extern "C" __global__ __launch_bounds__(256)
void k_dedup(const int* __restrict__ bcnt, const unsigned int* __restrict__ bbuf,
             unsigned int* __restrict__ srclist, int* __restrict__ cnt,
             float* __restrict__ inv){
  __shared__ unsigned int HT[HTS];   // 32KB
  __shared__ int dcur[128];
  const int tid = threadIdx.x;
  const int b   = blockIdx.x;
  const int d0  = b << 7;
  uint4* HT4 = reinterpret_cast<uint4*>(HT);
  #pragma unroll
  for (int r = 0; r < 8; ++r) HT4[r*256 + tid] = make_uint4(EMPTY,EMPTY,EMPTY,EMPTY);
  if (tid < 128) dcur[tid] = 0;
  __syncthreads();

  int n = bcnt[b]; if (n > CAPB) n = CAPB;
  const unsigned int* buf = bbuf + (size_t)b * CAPB;
  for (int k = tid; k < n; k += 256){
    unsigned int pk  = buf[k];
    unsigned int idx = mix32(pk) & (HTS-1);
    for (;;){
      unsigned int prev = atomicCAS(&HT[idx], EMPTY, pk);
      if (prev == EMPTY || prev == pk) break;
      idx = (idx + 1) & (HTS-1);
    }
  }
  if (tid < 128 && d0 + tid < NN){      // self loop (src=dst=d0+tid)
    unsigned int pk  = ((unsigned)(d0 + tid) << 7) | (unsigned)tid;
    unsigned int idx = mix32(pk) & (HTS-1);
    for (;;){
      unsigned int prev = atomicCAS(&HT[idx], EMPTY, pk);
      if (prev == EMPTY || prev == pk) break;
      idx = (idx + 1) & (HTS-1);
    }
  }
  __syncthreads();

  // single scan: compact + count
  for (int i = tid; i < HTS; i += 256){
    unsigned int v = HT[i];
    if (v != EMPTY){
      int dl  = v & 127;
      int pos = atomicAdd(&dcur[dl], 1);
      if (pos < CAP) srclist[(size_t)(d0 + dl) * CAP + pos] = v >> 7;
    }
  }
  __syncthreads();
  if (tid < 128 && d0 + tid < NN){
    int c = dcur[tid];
    cnt[d0 + tid] = c;
    inv[d0 + tid] = rsqrtf((float)c);
  }
}

// One wave per dst. lane = dim-QUAD (uint2 = 4 bf16); groups g=lane>>4 take
// edges j+4u+g. Nontemporal srclist loads + out stores keep hb L2-resident.
extern "C" __global__ __launch_bounds__(256)
void k_agg(const __hip_bfloat16* __restrict__ hb, const float* __restrict__ inv,
           const int* __restrict__ cnt, const unsigned int* __restrict__ srclist,
           float* __restrict__ out){
  __shared__ uint2 sv[4][CAP];   // .x = src, .y = f32 bits of inv[src]
  const int wv   = threadIdx.x >> 6;
  const int lane = threadIdx.x & 63;
  const int g    = lane >> 4;
  const int pl   = lane & 15;
  const int d    = blockIdx.x*4 + wv;
  if (d >= NN) return;
  const unsigned int* reg = srclist + (size_t)d * CAP;
  int c = cnt[d]; if (c > CAP) c = CAP;
  const int cp = (c + 15) & ~15;

  if (lane < c){
    unsigned s = __builtin_nontemporal_load(reg + lane);
    sv[wv][lane] = make_uint2(s, __float_as_uint(inv[s]));
  }
  if (64 + lane < c){
    unsigned s = __builtin_nontemporal_load(reg + 64 + lane);
    sv[wv][64 + lane] = make_uint2(s, __float_as_uint(inv[s]));
  }
  { int p = c + lane; if (p < cp) sv[wv][p] = make_uint2(0u, 0u); }

  const char* hbase = (const char*)hb;
  const int   boff  = pl << 3;    // byte offset of this dim quad within a row
  float4 acc[4];
  #pragma unroll
  for (int u=0;u<4;++u) acc[u] = make_float4(0.f,0.f,0.f,0.f);
  #pragma unroll 2
  for (int j = 0; j < cp; j += 16){
    #pragma unroll
    for (int u = 0; u < 4; ++u){
      uint2 e = sv[wv][j + 4*u + g];
      float w = __uint_as_float(e.y);
      uint2 hv = *reinterpret_cast<const uint2*>(hbase + ((size_t)e.x << 7) + boff);
      acc[u].x += w * __uint_as_float(hv.x << 16);
      acc[u].y += w * __uint_as_float(hv.x & 0xFFFF0000u);
      acc[u].z += w * __uint_as_float(hv.y << 16);
      acc[u].w += w * __uint_as_float(hv.y & 0xFFFF0000u);
    }
  }
  float4 r;
  r.x = (acc[0].x+acc[1].x)+(acc[2].x+acc[3].x);
  r.y = (acc[0].y+acc[1].y)+(acc[2].y+acc[3].y);
  r.z = (acc[0].z+acc[1].z)+(acc[2].z+acc[3].z);
  r.w = (acc[0].w+acc[1].w)+(acc[2].w+acc[3].w);
  r.x += __shfl_xor(r.x, 16); r.y += __shfl_xor(r.y, 16);
  r.z += __shfl_xor(r.z, 16); r.w += __shfl_xor(r.w, 16);
  r.x += __shfl_xor(r.x, 32); r.y += __shfl_xor(r.y, 32);
  r.z += __shfl_xor(r.z, 32); r.w += __shfl_xor(r.w, 32);
  if (g == 0){
    float iv = inv[d];
    fx4 o; o.x = r.x*iv; o.y = r.y*iv; o.z = r.z*iv; o.w = r.w*iv;
    __builtin_nontemporal_store(o, reinterpret_cast<fx4*>(&out[(size_t)d*64]) + pl);
  }
}

extern "C" void kernel_launch(void* const* d_in, const int* in_sizes, int n_in,
                              void* d_out, int out_size, void* d_ws, size_t ws_size,
                              hipStream_t stream){
  (void)in_sizes; (void)n_in; (void)out_size; (void)ws_size;
  const float* x  = (const float*)d_in[0];
  const int*   ei = (const int*)  d_in[1];
  const float* W  = (const float*)d_in[2];
  const float* b  = (const float*)d_in[3];
  float* out = (float*)d_out;

  char* ws = (char*)d_ws;
  __hip_bfloat16* hb      = (__hip_bfloat16*)ws;            // 12.8 MB
  float*          inv     = (float*)(ws + 12800000);        // 0.4 MB
  int*            cnt     = (int*)  (ws + 13200000);        // 0.4 MB
  unsigned int*   srclist = (unsigned int*)(ws + 13600000); // 51.2 MB
  int*            bcnt    = (int*)  (ws + 64800000);        // 4 KB
  unsigned int*   bbuf    = (unsigned int*)(ws + 64804096); // 16.0 MB (end ~80.8 MB)

  (void)hipMemsetAsync(bcnt, 0, NB * 4, stream);

  k_prep  <<<GBIN + GLIN, 256, 0, stream>>>(x, W, b, hb, ei, bcnt, bbuf);
  k_dedup <<<NB, 256, 0, stream>>>(bcnt, bbuf, srclist, cnt, inv);
  k_agg   <<<(NN + 3)/4, 256, 0, stream>>>(hb, inv, cnt, srclist, out);
}

// Round 11
// 145.454 us; speedup vs baseline: 1.1181x; 1.1181x over previous
//
#include <hip/hip_runtime.h>
#include <hip/hip_bf16.h>
#include <stdint.h>

#define NN 100000
#define EE 1600000
#define CAP 128           // srclist slots per dst (max unique in-degree ~70)
#define NB 782            // ceil(NN/128) dst buckets
#define HTS 8192          // per-bucket LDS hash slots
#define EMPTY 0xFFFFFFFFu
#define BCH 16384         // edge pairs per bin block
#define GBIN 98           // bin blocks: ceil(EE/BCH)
#define PRIV 96           // private slots per (bucket, bin-block); mean 42, 8.4 sigma
#define GLIN 1563         // linear blocks: ceil(NN/64)

typedef float fx4 __attribute__((ext_vector_type(4)));   // NT-store-compatible

__device__ __forceinline__ unsigned int mix32(unsigned int x){
  x ^= x >> 16; x *= 0x7feb352du;
  x ^= x >> 15; x *= 0x846ca68bu;
  x ^= x >> 16;
  return x;
}

// Fused linear+bin. Bin blocks FIRST (longest-job-first, only 98 of them).
// Binning uses ZERO global atomics: each bin block owns a private PRIV-slot
// slice of every bucket; LDS atomicAdd gives the final position directly.
extern "C" __global__ __launch_bounds__(256)
void k_prep(const float* __restrict__ x, const float* __restrict__ W,
            const float* __restrict__ bias, __hip_bfloat16* __restrict__ hb,
            const int* __restrict__ ei, int* __restrict__ gcnt,
            unsigned int* __restrict__ bbuf){
  __shared__ __align__(16) char sm[17920];
  const int tid = threadIdx.x;
  const int bid = blockIdx.x;
  const bool isbin = (bid < GBIN);
  const int sub = isbin ? bid : (bid - GBIN);

  if (!isbin){
    // ---------- linear: 64 nodes/block, W and x staged bf16 ----------
    __hip_bfloat16 (*wt)[72] = reinterpret_cast<__hip_bfloat16(*)[72]>(sm);        // 9216B wt[i][o]=W[o][i]
    __hip_bfloat16 (*xs)[68] = reinterpret_cast<__hip_bfloat16(*)[68]>(sm + 9216); // 8704B xs[i][n]
    const int lane = tid & 63;
    const int wv   = tid >> 6;
    #pragma unroll
    for (int r = 0; r < 16; ++r){
      int i = r*4 + wv;
      wt[i][lane] = __float2bfloat16(W[lane*64 + i]);
    }
    const int nbase = sub * 64;
    #pragma unroll
    for (int r = 0; r < 4; ++r){
      int idx = r*256 + tid;          // float4 slot in [64][16]
      int nl  = idx >> 4;
      int c4  = idx & 15;
      int n   = nbase + nl;
      float4 v = make_float4(0.f,0.f,0.f,0.f);
      if (n < NN) v = reinterpret_cast<const float4*>(x)[(size_t)n*16 + c4];
      xs[c4*4+0][nl] = __float2bfloat16(v.x);
      xs[c4*4+1][nl] = __float2bfloat16(v.y);
      xs[c4*4+2][nl] = __float2bfloat16(v.z);
      xs[c4*4+3][nl] = __float2bfloat16(v.w);
    }
    __syncthreads();

    const int og  = tid & 7;
    const int nl0 = (tid >> 3) * 2;   // 2 nodes per thread
    float acc[2][8];
    #pragma unroll
    for (int t=0;t<2;++t){
      #pragma unroll
      for (int j=0;j<8;++j) acc[t][j]=0.f;
    }
    #pragma unroll 4
    for (int i=0;i<64;++i){
      uint4 wq = *reinterpret_cast<const uint4*>(&wt[i][og*8]);
      float w0 = __uint_as_float(wq.x << 16), w1 = __uint_as_float(wq.x & 0xFFFF0000u);
      float w2 = __uint_as_float(wq.y << 16), w3 = __uint_as_float(wq.y & 0xFFFF0000u);
      float w4 = __uint_as_float(wq.z << 16), w5 = __uint_as_float(wq.z & 0xFFFF0000u);
      float w6 = __uint_as_float(wq.w << 16), w7 = __uint_as_float(wq.w & 0xFFFF0000u);
      unsigned xv = *reinterpret_cast<const unsigned*>(&xs[i][nl0]);  // 2 bf16
      float x0 = __uint_as_float(xv << 16);
      float x1 = __uint_as_float(xv & 0xFFFF0000u);
      acc[0][0] += x0*w0; acc[0][1] += x0*w1; acc[0][2] += x0*w2; acc[0][3] += x0*w3;
      acc[0][4] += x0*w4; acc[0][5] += x0*w5; acc[0][6] += x0*w6; acc[0][7] += x0*w7;
      acc[1][0] += x1*w0; acc[1][1] += x1*w1; acc[1][2] += x1*w2; acc[1][3] += x1*w3;
      acc[1][4] += x1*w4; acc[1][5] += x1*w5; acc[1][6] += x1*w6; acc[1][7] += x1*w7;
    }
    float4 b0 = reinterpret_cast<const float4*>(bias)[og*2];
    float4 b1 = reinterpret_cast<const float4*>(bias)[og*2+1];
    float bb[8] = {b0.x,b0.y,b0.z,b0.w,b1.x,b1.y,b1.z,b1.w};
    #pragma unroll
    for (int t=0;t<2;++t){
      int n = nbase + nl0 + t;
      if (n < NN){
        union { uint4 u4; __hip_bfloat16 v[8]; } pk;
        #pragma unroll
        for (int j=0;j<8;++j) pk.v[j] = __float2bfloat16(acc[t][j] + bb[j]);
        reinterpret_cast<uint4*>(&hb[(size_t)n*64])[og] = pk.u4;
      }
    }
  } else {
    // ---------- bin: 16384 pairs/block, private slices, no global atomics ----------
    int* bcur = reinterpret_cast<int*>(sm);   // [NB]
    for (int i = tid; i < NB; i += 256) bcur[i] = 0;
    __syncthreads();
    const int base4 = (sub * BCH) >> 2;
    const int4* ea4 = reinterpret_cast<const int4*>(ei);
    const int4* ec4 = reinterpret_cast<const int4*>(ei + EE);
    #pragma unroll 1
    for (int r = 0; r < 16; ++r){
      int idx = base4 + r*256 + tid;
      if (idx < (EE >> 2)){
        int4 A = ea4[idx], C = ec4[idx];
#define BIN1(a,c) { \
        int b1 = (c) >> 7, b2 = (a) >> 7; \
        int p1 = atomicAdd(&bcur[b1], 1); \
        int p2 = atomicAdd(&bcur[b2], 1); \
        if (p1 < PRIV) bbuf[((size_t)b1*GBIN + sub)*PRIV + p1] = ((unsigned)(a) << 7) | (unsigned)((c) & 127); \
        if (p2 < PRIV) bbuf[((size_t)b2*GBIN + sub)*PRIV + p2] = ((unsigned)(c) << 7) | (unsigned)((a) & 127); }
        BIN1(A.x, C.x) BIN1(A.y, C.y) BIN1(A.z, C.z) BIN1(A.w, C.w)
#undef BIN1
      }
    }
    __syncthreads();
    for (int bk = tid; bk < NB; bk += 256){
      int c = bcur[bk];
      gcnt[bk*GBIN + sub] = (c < PRIV) ? c : PRIV;
    }
  }
}

// One block per bucket: dedup its 98 private segments in an LDS hash,
// inject self loops, then one scan that compacts src lists and counts.
extern "C" __global__ __launch_bounds__(256)
void k_dedup(const int* __restrict__ gcnt, const unsigned int* __restrict__ bbuf,
             unsigned int* __restrict__ srclist, int* __restrict__ cnt,
             float* __restrict__ inv){
  __shared__ unsigned int HT[HTS];   // 32KB
  __shared__ int dcur[128];
  __shared__ int scnt[GBIN];
  const int tid = threadIdx.x;
  const int b   = blockIdx.x;
  const int d0  = b << 7;
  uint4* HT4 = reinterpret_cast<uint4*>(HT);
  #pragma unroll
  for (int r = 0; r < 8; ++r) HT4[r*256 + tid] = make_uint4(EMPTY,EMPTY,EMPTY,EMPTY);
  if (tid < 128) dcur[tid] = 0;
  if (tid < GBIN) scnt[tid] = gcnt[b*GBIN + tid];
  __syncthreads();

  const int wv   = tid >> 6;
  const int lane = tid & 63;
  // wave wv handles segments wv, wv+4, ... (lanes over entries; m<=PRIV=96)
  for (int seg = wv; seg < GBIN; seg += 4){
    int m = scnt[seg];
    const unsigned int* sb = bbuf + ((size_t)b*GBIN + seg)*PRIV;
    for (int k = lane; k < m; k += 64){
      unsigned int pk  = sb[k];
      unsigned int idx = mix32(pk) & (HTS-1);
      for (;;){
        unsigned int prev = atomicCAS(&HT[idx], EMPTY, pk);
        if (prev == EMPTY || prev == pk) break;
        idx = (idx + 1) & (HTS-1);
      }
    }
  }
  if (tid < 128 && d0 + tid < NN){      // self loop (src=dst=d0+tid)
    unsigned int pk  = ((unsigned)(d0 + tid) << 7) | (unsigned)tid;
    unsigned int idx = mix32(pk) & (HTS-1);
    for (;;){
      unsigned int prev = atomicCAS(&HT[idx], EMPTY, pk);
      if (prev == EMPTY || prev == pk) break;
      idx = (idx + 1) & (HTS-1);
    }
  }
  __syncthreads();

  // single scan: compact + count
  for (int i = tid; i < HTS; i += 256){
    unsigned int v = HT[i];
    if (v != EMPTY){
      int dl  = v & 127;
      int pos = atomicAdd(&dcur[dl], 1);
      if (pos < CAP) srclist[(size_t)(d0 + dl) * CAP + pos] = v >> 7;
    }
  }
  __syncthreads();
  if (tid < 128 && d0 + tid < NN){
    int c = dcur[tid];
    cnt[d0 + tid] = c;
    inv[d0 + tid] = rsqrtf((float)c);
  }
}

// One wave per dst. lane = dim-QUAD (uint2 = 4 bf16); groups g=lane>>4 take
// edges j+4u+g. Nontemporal srclist loads + out stores keep hb L2-resident.
extern "C" __global__ __launch_bounds__(256)
void k_agg(const __hip_bfloat16* __restrict__ hb, const float* __restrict__ inv,
           const int* __restrict__ cnt, const unsigned int* __restrict__ srclist,
           float* __restrict__ out){
  __shared__ uint2 sv[4][CAP];   // .x = src, .y = f32 bits of inv[src]
  const int wv   = threadIdx.x >> 6;
  const int lane = threadIdx.x & 63;
  const int g    = lane >> 4;
  const int pl   = lane & 15;
  const int d    = blockIdx.x*4 + wv;
  if (d >= NN) return;
  const unsigned int* reg = srclist + (size_t)d * CAP;
  int c = cnt[d]; if (c > CAP) c = CAP;
  const int cp = (c + 15) & ~15;

  if (lane < c){
    unsigned s = __builtin_nontemporal_load(reg + lane);
    sv[wv][lane] = make_uint2(s, __float_as_uint(inv[s]));
  }
  if (64 + lane < c){
    unsigned s = __builtin_nontemporal_load(reg + 64 + lane);
    sv[wv][64 + lane] = make_uint2(s, __float_as_uint(inv[s]));
  }
  { int p = c + lane; if (p < cp) sv[wv][p] = make_uint2(0u, 0u); }

  const char* hbase = (const char*)hb;
  const int   boff  = pl << 3;    // byte offset of this dim quad within a row
  float4 acc[4];
  #pragma unroll
  for (int u=0;u<4;++u) acc[u] = make_float4(0.f,0.f,0.f,0.f);
  #pragma unroll 2
  for (int j = 0; j < cp; j += 16){
    #pragma unroll
    for (int u = 0; u < 4; ++u){
      uint2 e = sv[wv][j + 4*u + g];
      float w = __uint_as_float(e.y);
      uint2 hv = *reinterpret_cast<const uint2*>(hbase + ((size_t)e.x << 7) + boff);
      acc[u].x += w * __uint_as_float(hv.x << 16);
      acc[u].y += w * __uint_as_float(hv.x & 0xFFFF0000u);
      acc[u].z += w * __uint_as_float(hv.y << 16);
      acc[u].w += w * __uint_as_float(hv.y & 0xFFFF0000u);
    }
  }
  float4 r;
  r.x = (acc[0].x+acc[1].x)+(acc[2].x+acc[3].x);
  r.y = (acc[0].y+acc[1].y)+(acc[2].y+acc[3].y);
  r.z = (acc[0].z+acc[1].z)+(acc[2].z+acc[3].z);
  r.w = (acc[0].w+acc[1].w)+(acc[2].w+acc[3].w);
  r.x += __shfl_xor(r.x, 16); r.y += __shfl_xor(r.y, 16);
  r.z += __shfl_xor(r.z, 16); r.w += __shfl_xor(r.w, 16);
  r.x += __shfl_xor(r.x, 32); r.y += __shfl_xor(r.y, 32);
  r.z += __shfl_xor(r.z, 32); r.w += __shfl_xor(r.w, 32);
  if (g == 0){
    float iv = inv[d];
    fx4 o; o.x = r.x*iv; o.y = r.y*iv; o.z = r.z*iv; o.w = r.w*iv;
    __builtin_nontemporal_store(o, reinterpret_cast<fx4*>(&out[(size_t)d*64]) + pl);
  }
}

extern "C" void kernel_launch(void* const* d_in, const int* in_sizes, int n_in,
                              void* d_out, int out_size, void* d_ws, size_t ws_size,
                              hipStream_t stream){
  (void)in_sizes; (void)n_in; (void)out_size; (void)ws_size;
  const float* x  = (const float*)d_in[0];
  const int*   ei = (const int*)  d_in[1];
  const float* W  = (const float*)d_in[2];
  const float* b  = (const float*)d_in[3];
  float* out = (float*)d_out;

  char* ws = (char*)d_ws;
  __hip_bfloat16* hb      = (__hip_bfloat16*)ws;            // 12.8 MB
  float*          inv     = (float*)(ws + 12800000);        // 0.4 MB
  int*            cnt     = (int*)  (ws + 13200000);        // 0.4 MB
  unsigned int*   srclist = (unsigned int*)(ws + 13600000); // 51.2 MB
  int*            gcnt    = (int*)  (ws + 64800000);        // 782*98*4 = 306 KB
  unsigned int*   bbuf    = (unsigned int*)(ws + 65200000); // 782*98*96*4 = 29.4 MB (end ~94.6 MB)

  k_prep  <<<GBIN + GLIN, 256, 0, stream>>>(x, W, b, hb, ei, gcnt, bbuf);
  k_dedup <<<NB, 256, 0, stream>>>(gcnt, bbuf, srclist, cnt, inv);
  k_agg   <<<(NN + 3)/4, 256, 0, stream>>>(hb, inv, cnt, srclist, out);
}